// Round 1
// baseline (1208.611 us; speedup 1.0000x reference)
//
#include <hip/hip_runtime.h>
#include <cstdint>
#include <cstddef>

#define EPI_IN    0   // y = relu(xW + b)
#define EPI_SCALE 1   // y = inv[r] * (xW + b)
#define EPI_LNRES 2   // y = relu(LN(xW + b + res))
#define EPI_NONE  3   // y = xW + b          (NOUT=64)

__device__ __forceinline__ float wred(float v) {
#pragma unroll
  for (int m = 32; m >= 1; m >>= 1) v += __shfl_xor(v, m, 64);
  return v;
}

// ---------------- CSR build: hierarchical exclusive scan of int(degree) ----
__global__ void scan_block_k(const float* __restrict__ deg, int* __restrict__ offs,
                             int* __restrict__ bsum, int N) {
  __shared__ int sh[256];
  int tid = threadIdx.x;
  int i = blockIdx.x * 256 + tid;
  int c = (i < N) ? (int)(deg[i] + 0.5f) : 0;
  int val = c;
  for (int off = 1; off < 256; off <<= 1) {
    sh[tid] = val; __syncthreads();
    if (tid >= off) val += sh[tid - off];
    __syncthreads();
  }
  if (i < N) offs[i] = val - c;          // exclusive within block
  if (tid == 255) bsum[blockIdx.x] = val;
}

__global__ void scan_bsum_k(int* __restrict__ bsum, int nb) {
  __shared__ int sh[1024];
  int tid = threadIdx.x;
  int c = (tid < nb) ? bsum[tid] : 0;
  int val = c;
  for (int off = 1; off < 1024; off <<= 1) {
    sh[tid] = val; __syncthreads();
    if (tid >= off) val += sh[tid - off];
    __syncthreads();
  }
  if (tid < nb) bsum[tid] = val - c;     // exclusive block bases
}

__global__ void scan_add_k(int* __restrict__ offs, const int* __restrict__ bsum,
                           int* __restrict__ cursor, float* __restrict__ inv,
                           const float* __restrict__ deg, int N, int E) {
  int i = blockIdx.x * 256 + threadIdx.x;
  if (i < N) {
    int o = offs[i] + bsum[i >> 8];
    offs[i] = o;
    cursor[i] = o;
    inv[i] = rsqrtf(deg[i] + 1.0f);
  } else if (i == N) {
    offs[N] = E;
  }
}

__global__ void fill_csr_k(const int* __restrict__ src, const int* __restrict__ dst,
                           int* __restrict__ cursor, int* __restrict__ col, int E) {
  int e = blockIdx.x * 256 + threadIdx.x;
  if (e < E) {
    int d = dst[e];
    int p = atomicAdd(&cursor[d], 1);
    col[p] = src[e];
  }
}

// ---------------- SpMM: agg[d] = inv[d] * (msc[d] + sum_{s in CSR[d]} msc[s]) ---
__global__ __launch_bounds__(256) void spmm_k(
    const float* __restrict__ msc, const int* __restrict__ offs,
    const int* __restrict__ col, const float* __restrict__ inv,
    float* __restrict__ agg, int N) {
  const int wid = threadIdx.x >> 6, lane = threadIdx.x & 63;
  const int d = blockIdx.x * 4 + wid;
  if (d >= N) return;
  const float2* m2 = (const float2*)msc;
  int s0 = offs[d], s1 = offs[d + 1];
  float2 acc = m2[(size_t)d * 64 + lane];     // self loop: msc[d]
  for (int base = s0; base < s1; base += 64) {
    int idx = (base + lane < s1) ? col[base + lane] : 0;
    int n = min(64, s1 - base);
    for (int j = 0; j < n; ++j) {
      int s = __shfl(idx, j, 64);
      float2 v = m2[(size_t)s * 64 + lane];
      acc.x += v.x; acc.y += v.y;
    }
  }
  float iv = inv[d];
  ((float2*)agg)[(size_t)d * 64 + lane] = make_float2(acc.x * iv, acc.y * iv);
}

// ---------------- dense GEMM [N,128] @ [128,NOUT] + fused epilogues ----------
template <int NOUT, int EPI>
__global__ __launch_bounds__(256) void gemm_epi(
    const float* __restrict__ X, const float* __restrict__ Wg,
    const float* __restrict__ bias, float* __restrict__ Y,
    const float* __restrict__ res,   // inv (EPI_SCALE) or residual rows (EPI_LNRES)
    const float* __restrict__ lng, const float* __restrict__ lnb, int N) {
  __shared__ float xs[32][128];
  __shared__ float wl[32 * NOUT];
  const int tid = threadIdx.x;
  const int row0 = blockIdx.x * 32;

  // stage 32 X rows (float4)
  for (int i = tid; i < 32 * 32; i += 256) {
    int r = i >> 5, c4 = i & 31;
    int gr = row0 + r;
    float4 v = make_float4(0.f, 0.f, 0.f, 0.f);
    if (gr < N) v = ((const float4*)(X + (size_t)gr * 128))[c4];
    ((float4*)&xs[r][0])[c4] = v;
  }

  const int wid = tid >> 6, lane = tid & 63;
  const int rb = wid * 8;
  float2 acc[8];
#pragma unroll
  for (int r = 0; r < 8; ++r) acc[r] = make_float2(0.f, 0.f);

  for (int kc = 0; kc < 4; ++kc) {
    __syncthreads();
    for (int i = tid; i < 32 * NOUT / 4; i += 256)
      ((float4*)wl)[i] = ((const float4*)(Wg + (size_t)kc * 32 * NOUT))[i];
    __syncthreads();
#pragma unroll
    for (int k4 = 0; k4 < 32; k4 += 4) {
      if constexpr (NOUT == 128) {
        float2 w0 = *(const float2*)&wl[(k4 + 0) * 128 + lane * 2];
        float2 w1 = *(const float2*)&wl[(k4 + 1) * 128 + lane * 2];
        float2 w2 = *(const float2*)&wl[(k4 + 2) * 128 + lane * 2];
        float2 w3 = *(const float2*)&wl[(k4 + 3) * 128 + lane * 2];
#pragma unroll
        for (int r = 0; r < 8; ++r) {
          float4 xv = *(const float4*)&xs[rb + r][kc * 32 + k4];
          acc[r].x += xv.x * w0.x + xv.y * w1.x + xv.z * w2.x + xv.w * w3.x;
          acc[r].y += xv.x * w0.y + xv.y * w1.y + xv.z * w2.y + xv.w * w3.y;
        }
      } else {
        float w0 = wl[(k4 + 0) * 64 + lane];
        float w1 = wl[(k4 + 1) * 64 + lane];
        float w2 = wl[(k4 + 2) * 64 + lane];
        float w3 = wl[(k4 + 3) * 64 + lane];
#pragma unroll
        for (int r = 0; r < 8; ++r) {
          float4 xv = *(const float4*)&xs[rb + r][kc * 32 + k4];
          acc[r].x += xv.x * w0 + xv.y * w1 + xv.z * w2 + xv.w * w3;
        }
      }
    }
  }

  // epilogue (per wave: rows rb..rb+7, lane -> cols)
  if constexpr (NOUT == 128) {
    float2 b2 = *(const float2*)&bias[lane * 2];
    for (int r = 0; r < 8; ++r) {
      int gr = row0 + rb + r;
      if (gr >= N) break;                 // wave-uniform
      float2 t = make_float2(acc[r].x + b2.x, acc[r].y + b2.y);
      if constexpr (EPI == EPI_IN) {
        t.x = fmaxf(t.x, 0.f); t.y = fmaxf(t.y, 0.f);
        ((float2*)(Y + (size_t)gr * 128))[lane] = t;
      } else if constexpr (EPI == EPI_SCALE) {
        float iv = res[gr];
        ((float2*)(Y + (size_t)gr * 128))[lane] = make_float2(t.x * iv, t.y * iv);
      } else {  // EPI_LNRES
        float2 h0 = ((const float2*)(res + (size_t)gr * 128))[lane];
        t.x += h0.x; t.y += h0.y;
        float mean = wred(t.x + t.y) * (1.f / 128.f);
        float dx = t.x - mean, dy = t.y - mean;
        float var = wred(dx * dx + dy * dy) * (1.f / 128.f);
        float rstd = rsqrtf(var + 1e-5f);
        float2 g2 = *(const float2*)&lng[lane * 2];
        float2 bb = *(const float2*)&lnb[lane * 2];
        float y0 = fmaxf(dx * rstd * g2.x + bb.x, 0.f);
        float y1 = fmaxf(dy * rstd * g2.y + bb.y, 0.f);
        ((float2*)(Y + (size_t)gr * 128))[lane] = make_float2(y0, y1);
      }
    }
  } else {
    float bv = bias[lane];
    for (int r = 0; r < 8; ++r) {
      int gr = row0 + rb + r;
      if (gr >= N) break;
      Y[(size_t)gr * 64 + lane] = acc[r].x + bv;
    }
  }
}

// ---------------- final LN (no relu, no residual) ---------------------------
__global__ __launch_bounds__(256) void ln_final_k(
    const float* __restrict__ H, const float* __restrict__ g,
    const float* __restrict__ b, float* __restrict__ O, int N) {
  const int wid = threadIdx.x >> 6, lane = threadIdx.x & 63;
  const int d = blockIdx.x * 4 + wid;
  if (d >= N) return;
  float2 t = ((const float2*)(H + (size_t)d * 128))[lane];
  float mean = wred(t.x + t.y) * (1.f / 128.f);
  float dx = t.x - mean, dy = t.y - mean;
  float var = wred(dx * dx + dy * dy) * (1.f / 128.f);
  float rstd = rsqrtf(var + 1e-5f);
  float2 g2 = *(const float2*)&g[lane * 2];
  float2 b2 = *(const float2*)&b[lane * 2];
  ((float2*)(O + (size_t)d * 128))[lane] =
      make_float2(dx * rstd * g2.x + b2.x, dy * rstd * g2.y + b2.y);
}

// ---------------------------------------------------------------------------
extern "C" void kernel_launch(void* const* d_in, const int* in_sizes, int n_in,
                              void* d_out, int out_size, void* d_ws, size_t ws_size,
                              hipStream_t stream) {
  (void)n_in; (void)out_size; (void)ws_size;
  const float* x      = (const float*)d_in[0];
  const int*   eidx   = (const int*)d_in[1];
  const float* degree = (const float*)d_in[2];
  const float* Win    = (const float*)d_in[3];
  const float* b_in   = (const float*)d_in[4];
  const float* W1     = (const float*)d_in[5];
  const float* b1     = (const float*)d_in[6];
  const float* W2     = (const float*)d_in[7];
  const float* b2     = (const float*)d_in[8];
  const float* ln_g   = (const float*)d_in[9];
  const float* ln_b   = (const float*)d_in[10];
  const float* out_g  = (const float*)d_in[11];
  const float* out_b  = (const float*)d_in[12];
  const float* Wout   = (const float*)d_in[13];
  const float* b_out  = (const float*)d_in[14];

  const int N = in_sizes[0] / 128;
  const int E = in_sizes[1] / 2;
  const int* esrc = eidx;
  const int* edst = eidx + E;

  char* p = (char*)d_ws;
  auto alloc = [&](size_t bytes) {
    char* q = p;
    p += (bytes + 255) & ~(size_t)255;
    return q;
  };
  float* inv    = (float*)alloc((size_t)N * 4);
  int*   offs   = (int*)alloc(((size_t)N + 1) * 4);
  int*   cursor = (int*)alloc((size_t)N * 4);
  int*   bsum   = (int*)alloc(1024 * 4);
  int*   col    = (int*)alloc((size_t)E * 4);
  float* bufA   = (float*)alloc((size_t)N * 128 * 4);
  float* bufB   = (float*)alloc((size_t)N * 128 * 4);
  float* agg    = (float*)alloc((size_t)N * 128 * 4);

  const int nb = (N + 255) / 256;
  scan_block_k<<<nb, 256, 0, stream>>>(degree, offs, bsum, N);
  scan_bsum_k<<<1, 1024, 0, stream>>>(bsum, nb);
  scan_add_k<<<(N + 256) / 256, 256, 0, stream>>>(offs, bsum, cursor, inv, degree, N, E);
  fill_csr_k<<<(E + 255) / 256, 256, 0, stream>>>(esrc, edst, cursor, col, E);

  const int gemmGrid = (N + 31) / 32;
  const int rowGrid  = (N + 3) / 4;

  float* A = bufA;  // current h
  float* B = bufB;  // scratch / next h
  gemm_epi<128, EPI_IN><<<gemmGrid, 256, 0, stream>>>(x, Win, b_in, A, nullptr, nullptr, nullptr, N);
  for (int l = 0; l < 3; ++l) {
    gemm_epi<128, EPI_SCALE><<<gemmGrid, 256, 0, stream>>>(
        A, W1 + (size_t)l * 128 * 128, b1 + l * 128, B, inv, nullptr, nullptr, N);
    spmm_k<<<rowGrid, 256, 0, stream>>>(B, offs, col, inv, agg, N);
    gemm_epi<128, EPI_LNRES><<<gemmGrid, 256, 0, stream>>>(
        agg, W2 + (size_t)l * 128 * 128, b2 + l * 128, B, A,
        ln_g + l * 128, ln_b + l * 128, N);
    float* t = A; A = B; B = t;   // A = new h
  }
  ln_final_k<<<rowGrid, 256, 0, stream>>>(A, out_g, out_b, B, N);
  gemm_epi<64, EPI_NONE><<<gemmGrid, 256, 0, stream>>>(
      B, Wout, b_out, (float*)d_out, nullptr, nullptr, nullptr, N);
}

// Round 2
// 529.878 us; speedup vs baseline: 2.2809x; 2.2809x over previous
//
#include <hip/hip_runtime.h>
#include <cstdint>
#include <cstddef>

typedef unsigned short u16;
typedef unsigned int u32;
typedef __attribute__((ext_vector_type(2))) unsigned short u16x2;
typedef __attribute__((ext_vector_type(4))) unsigned short u16x4;
typedef __attribute__((ext_vector_type(8))) unsigned short u16x8;
typedef __attribute__((ext_vector_type(8))) __bf16 bf16x8;
typedef __attribute__((ext_vector_type(4))) float f32x4;

#define PREP_F32  0
#define PREP_BF16 1
#define PREP_LN   2
#define EPI_IN    0   // y = relu(xW + b)                -> fp32
#define EPI_SCALE 1   // y = inv[r]*(xW + b)             -> bf16
#define EPI_LNRES 2   // y = relu(LN(xW + b + res))      -> fp32 (in-place ok)
#define EPI_NONE  3   // y = xW + b                      -> fp32 (NOUT=64)

__device__ __forceinline__ float wred(float v) {
#pragma unroll
  for (int m = 32; m >= 1; m >>= 1) v += __shfl_xor(v, m, 64);
  return v;
}
__device__ __forceinline__ u16 f2bf(float f) {
  u32 u = __float_as_uint(f);
  u += 0x7fffu + ((u >> 16) & 1u);
  return (u16)(u >> 16);
}
__device__ __forceinline__ float bflo(u32 u) { return __uint_as_float(u << 16); }
__device__ __forceinline__ float bfhi(u32 u) { return __uint_as_float(u & 0xffff0000u); }
__device__ __forceinline__ u32 pack2(float a, float b) {
  u32 ua = __float_as_uint(a); ua += 0x7fffu + ((ua >> 16) & 1u);
  u32 ub = __float_as_uint(b); ub += 0x7fffu + ((ub >> 16) & 1u);
  return (ua >> 16) | (ub & 0xffff0000u);
}

// ---------------- CSR build: hierarchical exclusive scan of int(degree) ----
__global__ void scan_block_k(const float* __restrict__ deg, int* __restrict__ offs,
                             int* __restrict__ bsum, int N) {
  __shared__ int sh[256];
  int tid = threadIdx.x;
  int i = blockIdx.x * 256 + tid;
  int c = (i < N) ? (int)(deg[i] + 0.5f) : 0;
  int val = c;
  for (int off = 1; off < 256; off <<= 1) {
    sh[tid] = val; __syncthreads();
    if (tid >= off) val += sh[tid - off];
    __syncthreads();
  }
  if (i < N) offs[i] = val - c;
  if (tid == 255) bsum[blockIdx.x] = val;
}

__global__ void scan_bsum_k(int* __restrict__ bsum, int nb) {
  __shared__ int sh[1024];
  int tid = threadIdx.x;
  int c = (tid < nb) ? bsum[tid] : 0;
  int val = c;
  for (int off = 1; off < 1024; off <<= 1) {
    sh[tid] = val; __syncthreads();
    if (tid >= off) val += sh[tid - off];
    __syncthreads();
  }
  if (tid < nb) bsum[tid] = val - c;
}

__global__ void scan_add_k(int* __restrict__ offs, const int* __restrict__ bsum,
                           int* __restrict__ cursor, float* __restrict__ inv,
                           const float* __restrict__ deg, int N, int E) {
  int i = blockIdx.x * 256 + threadIdx.x;
  if (i < N) {
    int o = offs[i] + bsum[i >> 8];
    offs[i] = o;
    cursor[i] = o;
    inv[i] = rsqrtf(deg[i] + 1.0f);
  } else if (i == N) {
    offs[N] = E;
  }
}

__global__ void fill_csr_k(const int* __restrict__ src, const int* __restrict__ dst,
                           int* __restrict__ cursor, int* __restrict__ col, int E) {
  int e = blockIdx.x * 256 + threadIdx.x;
  if (e < E) {
    int d = dst[e];
    int p = atomicAdd(&cursor[d], 1);
    col[p] = src[e];
  }
}

// ---------------- weight pre-pack: fp32 [128][ncol] -> bf16 MFMA fragments ----
// layout: P[((kc*NT + nt)*64 + lane)*8 + j], k = kc*32 + 4*(lane>>4) + (j&3) + 16*(j>>2),
//         n = nt*16 + (lane&15)
__global__ void pack_w_k(const float* __restrict__ W, u16* __restrict__ P, int ncol) {
  int t = blockIdx.x * 256 + threadIdx.x;
  int NT = ncol >> 4;
  int total = 4 * NT * 64;
  if (t >= total) return;
  int lane = t & 63;
  int tmp = t >> 6;
  int nt = tmp % NT, kc = tmp / NT;
  int n = nt * 16 + (lane & 15);
  int kb = kc * 32 + ((lane >> 4) << 2);
  u16* dst = P + (size_t)t * 8;
#pragma unroll
  for (int j = 0; j < 8; ++j) {
    int k = kb + (j & 3) + ((j >> 2) << 4);
    dst[j] = f2bf(W[(size_t)k * ncol + n]);
  }
}

// ---------------- SpMM (bf16): agg[d] = inv[d]*(msc[d] + sum msc[src]) -------
__global__ __launch_bounds__(256) void spmm_k(
    const u32* __restrict__ msc, const int* __restrict__ offs,
    const int* __restrict__ col, const float* __restrict__ inv,
    u32* __restrict__ agg, int N) {
  const int wid = threadIdx.x >> 6, lane = threadIdx.x & 63;
  const int d = blockIdx.x * 4 + wid;
  if (d >= N) return;
  u32 u = msc[(size_t)d * 64 + lane];
  float ax = bflo(u), ay = bfhi(u);       // self loop
  int s0 = offs[d], s1 = offs[d + 1];
  for (int base = s0; base < s1; base += 64) {
    int idx = (base + lane < s1) ? col[base + lane] : 0;
    int n = min(64, s1 - base);
    int j = 0;
    for (; j + 1 < n; j += 2) {
      int sa = __shfl(idx, j, 64);
      int sb = __shfl(idx, j + 1, 64);
      u32 va = msc[(size_t)sa * 64 + lane];
      u32 vb = msc[(size_t)sb * 64 + lane];
      ax += bflo(va) + bflo(vb);
      ay += bfhi(va) + bfhi(vb);
    }
    if (j < n) {
      int sa = __shfl(idx, j, 64);
      u32 va = msc[(size_t)sa * 64 + lane];
      ax += bflo(va); ay += bfhi(va);
    }
  }
  float iv = inv[d];
  agg[(size_t)d * 64 + lane] = pack2(ax * iv, ay * iv);
}

// ---------------- MFMA GEMM: [N,128] @ [128,NOUT] + fused prep/epilogue ------
// block = 256 thr (4 waves), 32 rows/block. N must be a multiple of 32 (100000 is).
template <int NOUT, int PREP, int EPI>
__global__ __launch_bounds__(256) void gemm_mfma(
    const void* __restrict__ Xv, const u16* __restrict__ Wp,
    const float* __restrict__ bias, void* __restrict__ Yv,
    const float* __restrict__ res,      // inv (SCALE) or residual h (LNRES, may alias Yv)
    const float* __restrict__ g1, const float* __restrict__ lb1,  // LN params (prep or epi)
    int N) {
  constexpr int NT = NOUT / 16;
  __shared__ union {
    u16  xs[32][136];   // A tile, bf16, +8 pad
    float cs[32][132];  // LNRES epilogue staging, +4 pad
  } sh;
  const int tid = threadIdx.x;
  const int lane = tid & 63, wid = tid >> 6;
  const int row0 = blockIdx.x * 32;

  // ---- stage A tile into xs (bf16) ----
  if constexpr (PREP == PREP_F32) {
    const float* X = (const float*)Xv;
    for (int i = tid; i < 1024; i += 256) {
      int r = i >> 5, c4 = i & 31;
      float4 v = ((const float4*)(X + (size_t)(row0 + r) * 128))[c4];
      u16x4 o = {f2bf(v.x), f2bf(v.y), f2bf(v.z), f2bf(v.w)};
      *(u16x4*)&sh.xs[r][c4 * 4] = o;
    }
  } else if constexpr (PREP == PREP_BF16) {
    const u16x4* X = (const u16x4*)Xv;
    for (int i = tid; i < 1024; i += 256) {
      int r = i >> 5, c4 = i & 31;
      *(u16x4*)&sh.xs[r][c4 * 4] = X[(size_t)(row0 + r) * 32 + c4];
    }
  } else {  // PREP_LN: wave w normalizes rows w*8..w*8+7 with g1/lb1
    const float* X = (const float*)Xv;
    float2 gg = *(const float2*)&g1[lane * 2];
    float2 bb = *(const float2*)&lb1[lane * 2];
    for (int rr = 0; rr < 8; ++rr) {
      int r = wid * 8 + rr;
      float2 t = ((const float2*)(X + (size_t)(row0 + r) * 128))[lane];
      float mean = wred(t.x + t.y) * (1.f / 128.f);
      float dx = t.x - mean, dy = t.y - mean;
      float var = wred(dx * dx + dy * dy) * (1.f / 128.f);
      float rstd = rsqrtf(var + 1e-5f);
      u16x2 o = {f2bf(dx * rstd * gg.x + bb.x), f2bf(dy * rstd * gg.y + bb.y)};
      *(u16x2*)&sh.xs[r][lane * 2] = o;
    }
  }
  __syncthreads();

  // ---- MFMA main loop ----
  constexpr int NTW = (NOUT == 128) ? 4 : 2;
  const int m0  = (NOUT == 128) ? ((wid >> 1) << 4) : ((wid & 1) << 4);
  const int ntb = (NOUT == 128) ? ((wid & 1) << 2) : ((wid >> 1) << 1);

  f32x4 acc[NTW];
#pragma unroll
  for (int t = 0; t < NTW; ++t) acc[t] = (f32x4){0.f, 0.f, 0.f, 0.f};

  const int ar  = m0 + (lane & 15);
  const int akb = (lane >> 4) << 2;
  const bf16x8* Bp = (const bf16x8*)Wp;
#pragma unroll
  for (int kc = 0; kc < 4; ++kc) {
    u16x4 lo = *(const u16x4*)&sh.xs[ar][kc * 32 + akb];
    u16x4 hi = *(const u16x4*)&sh.xs[ar][kc * 32 + akb + 16];
    u16x8 av;
#pragma unroll
    for (int j = 0; j < 4; ++j) { av[j] = lo[j]; av[j + 4] = hi[j]; }
    bf16x8 a = __builtin_bit_cast(bf16x8, av);
#pragma unroll
    for (int t = 0; t < NTW; ++t) {
      bf16x8 b = Bp[(kc * NT + ntb + t) * 64 + lane];
      acc[t] = __builtin_amdgcn_mfma_f32_16x16x32_bf16(a, b, acc[t], 0, 0, 0);
    }
  }

  // ---- epilogue ----
  // C/D layout (m89): col = lane&15, row = 4*(lane>>4) + reg
  const int cb = lane & 15;
  const int rg = (lane >> 4) << 2;
  if constexpr (EPI == EPI_IN) {
    float* Y = (float*)Yv;
#pragma unroll
    for (int t = 0; t < NTW; ++t) {
      int col = (ntb + t) * 16 + cb;
      float bv = bias[col];
#pragma unroll
      for (int r = 0; r < 4; ++r) {
        int gr = row0 + m0 + rg + r;
        Y[(size_t)gr * NOUT + col] = fmaxf(acc[t][r] + bv, 0.f);
      }
    }
  } else if constexpr (EPI == EPI_NONE) {
    float* Y = (float*)Yv;
#pragma unroll
    for (int t = 0; t < NTW; ++t) {
      int col = (ntb + t) * 16 + cb;
      float bv = bias[col];
#pragma unroll
      for (int r = 0; r < 4; ++r) {
        int gr = row0 + m0 + rg + r;
        Y[(size_t)gr * NOUT + col] = acc[t][r] + bv;
      }
    }
  } else if constexpr (EPI == EPI_SCALE) {
    u16* Y = (u16*)Yv;
#pragma unroll
    for (int t = 0; t < NTW; ++t) {
      int col = (ntb + t) * 16 + cb;
      float bv = bias[col];
#pragma unroll
      for (int r = 0; r < 4; ++r) {
        int gr = row0 + m0 + rg + r;
        Y[(size_t)gr * NOUT + col] = f2bf((acc[t][r] + bv) * res[gr]);
      }
    }
  } else {  // EPI_LNRES: stage to cs, then row-wise residual+LN+relu
    __syncthreads();  // xs (union alias) may still be read by other waves
#pragma unroll
    for (int t = 0; t < NTW; ++t) {
      int col = (ntb + t) * 16 + cb;
      float bv = bias[col];
#pragma unroll
      for (int r = 0; r < 4; ++r) sh.cs[m0 + rg + r][col] = acc[t][r] + bv;
    }
    __syncthreads();
    float* Y = (float*)Yv;
    float2 gg = *(const float2*)&g1[lane * 2];
    float2 bb = *(const float2*)&lb1[lane * 2];
    for (int rr = 0; rr < 8; ++rr) {
      int r = wid * 8 + rr;
      int gr = row0 + r;
      float2 t2 = *(const float2*)&sh.cs[r][lane * 2];
      float2 h0 = ((const float2*)(res + (size_t)gr * 128))[lane];
      float tx = t2.x + h0.x, ty = t2.y + h0.y;
      float mean = wred(tx + ty) * (1.f / 128.f);
      float dx = tx - mean, dy = ty - mean;
      float var = wred(dx * dx + dy * dy) * (1.f / 128.f);
      float rstd = rsqrtf(var + 1e-5f);
      float y0 = fmaxf(dx * rstd * gg.x + bb.x, 0.f);
      float y1 = fmaxf(dy * rstd * gg.y + bb.y, 0.f);
      ((float2*)(Y + (size_t)gr * 128))[lane] = make_float2(y0, y1);
    }
  }
}

// ---------------------------------------------------------------------------
extern "C" void kernel_launch(void* const* d_in, const int* in_sizes, int n_in,
                              void* d_out, int out_size, void* d_ws, size_t ws_size,
                              hipStream_t stream) {
  (void)n_in; (void)out_size; (void)ws_size;
  const float* x      = (const float*)d_in[0];
  const int*   eidx   = (const int*)d_in[1];
  const float* degree = (const float*)d_in[2];
  const float* Win    = (const float*)d_in[3];
  const float* b_in   = (const float*)d_in[4];
  const float* W1     = (const float*)d_in[5];
  const float* b1     = (const float*)d_in[6];
  const float* W2     = (const float*)d_in[7];
  const float* b2     = (const float*)d_in[8];
  const float* ln_g   = (const float*)d_in[9];
  const float* ln_b   = (const float*)d_in[10];
  const float* out_g  = (const float*)d_in[11];
  const float* out_b  = (const float*)d_in[12];
  const float* Wout   = (const float*)d_in[13];
  const float* b_out  = (const float*)d_in[14];

  const int N = in_sizes[0] / 128;
  const int E = in_sizes[1] / 2;
  const int* esrc = eidx;
  const int* edst = eidx + E;

  char* p = (char*)d_ws;
  auto alloc = [&](size_t bytes) {
    char* q = p;
    p += (bytes + 255) & ~(size_t)255;
    return q;
  };
  float* inv    = (float*)alloc((size_t)N * 4);
  int*   offs   = (int*)alloc(((size_t)N + 1) * 4);
  int*   cursor = (int*)alloc((size_t)N * 4);
  int*   bsum   = (int*)alloc(1024 * 4);
  int*   col    = (int*)alloc((size_t)E * 4);
  float* h      = (float*)alloc((size_t)N * 128 * 4);   // fp32 residual stream
  u32*   msc    = (u32*)alloc((size_t)N * 128 * 2);     // bf16
  u32*   agg    = (u32*)alloc((size_t)N * 128 * 2);     // bf16
  u16*   pWin   = (u16*)alloc(4 * 8 * 64 * 8 * 2);
  u16*   pWout  = (u16*)alloc(4 * 4 * 64 * 8 * 2);
  u16*   pW1    = (u16*)alloc(3 * 4 * 8 * 64 * 8 * 2);
  u16*   pW2    = (u16*)alloc(3 * 4 * 8 * 64 * 8 * 2);

  // weight packing (tiny)
  pack_w_k<<<8, 256, 0, stream>>>(Win, pWin, 128);
  for (int l = 0; l < 3; ++l) {
    pack_w_k<<<8, 256, 0, stream>>>(W1 + (size_t)l * 128 * 128, pW1 + (size_t)l * 16384, 128);
    pack_w_k<<<8, 256, 0, stream>>>(W2 + (size_t)l * 128 * 128, pW2 + (size_t)l * 16384, 128);
  }
  pack_w_k<<<4, 256, 0, stream>>>(Wout, pWout, 64);

  // CSR build
  const int nb = (N + 255) / 256;
  scan_block_k<<<nb, 256, 0, stream>>>(degree, offs, bsum, N);
  scan_bsum_k<<<1, 1024, 0, stream>>>(bsum, nb);
  scan_add_k<<<(N + 256) / 256, 256, 0, stream>>>(offs, bsum, cursor, inv, degree, N, E);
  fill_csr_k<<<(E + 255) / 256, 256, 0, stream>>>(esrc, edst, cursor, col, E);

  const int gemmGrid = (N + 31) / 32;
  const int rowGrid  = (N + 3) / 4;

  gemm_mfma<128, PREP_F32, EPI_IN><<<gemmGrid, 256, 0, stream>>>(
      x, pWin, b_in, h, nullptr, nullptr, nullptr, N);
  for (int l = 0; l < 3; ++l) {
    gemm_mfma<128, PREP_F32, EPI_SCALE><<<gemmGrid, 256, 0, stream>>>(
        h, pW1 + (size_t)l * 16384, b1 + l * 128, msc, inv, nullptr, nullptr, N);
    spmm_k<<<rowGrid, 256, 0, stream>>>(msc, offs, col, inv, agg, N);
    gemm_mfma<128, PREP_BF16, EPI_LNRES><<<gemmGrid, 256, 0, stream>>>(
        agg, pW2 + (size_t)l * 16384, b2 + l * 128, h, h,
        ln_g + l * 128, ln_b + l * 128, N);
  }
  gemm_mfma<64, PREP_LN, EPI_NONE><<<gemmGrid, 256, 0, stream>>>(
      h, pWout, b_out, d_out, nullptr, out_g, out_b, N);
}

// Round 3
// 458.449 us; speedup vs baseline: 2.6363x; 1.1558x over previous
//
#include <hip/hip_runtime.h>
#include <cstdint>
#include <cstddef>

typedef unsigned short u16;
typedef unsigned int u32;
typedef __attribute__((ext_vector_type(2))) unsigned short u16x2;
typedef __attribute__((ext_vector_type(4))) unsigned short u16x4;
typedef __attribute__((ext_vector_type(8))) unsigned short u16x8;
typedef __attribute__((ext_vector_type(8))) __bf16 bf16x8;
typedef __attribute__((ext_vector_type(4))) float f32x4;

#define PREP_F32  0
#define PREP_BF16 1
#define PREP_LN   2
#define EPI_IN    0   // y = relu(xW + b)                -> fp32
#define EPI_SCALE 1   // y = inv[r]*(xW + b)             -> bf16
#define EPI_LNRES 2   // y = relu(LN(xW + b + res))      -> fp32 (in-place ok)
#define EPI_NONE  3   // y = xW + b                      -> fp32 (NOUT=64)

__device__ __forceinline__ float wred(float v) {
#pragma unroll
  for (int m = 32; m >= 1; m >>= 1) v += __shfl_xor(v, m, 64);
  return v;
}
__device__ __forceinline__ u16 f2bf(float f) {
  u32 u = __float_as_uint(f);
  u += 0x7fffu + ((u >> 16) & 1u);
  return (u16)(u >> 16);
}
__device__ __forceinline__ float bflo(u32 u) { return __uint_as_float(u << 16); }
__device__ __forceinline__ float bfhi(u32 u) { return __uint_as_float(u & 0xffff0000u); }
__device__ __forceinline__ u32 pack2(float a, float b) {
  u32 ua = __float_as_uint(a); ua += 0x7fffu + ((ua >> 16) & 1u);
  u32 ub = __float_as_uint(b); ub += 0x7fffu + ((ub >> 16) & 1u);
  return (ua >> 16) | (ub & 0xffff0000u);
}

// ---------------- CSR build: hierarchical exclusive scan of int(degree) ----
__global__ void scan_block_k(const float* __restrict__ deg, int* __restrict__ offs,
                             int* __restrict__ bsum, int N) {
  __shared__ int sh[256];
  int tid = threadIdx.x;
  int i = blockIdx.x * 256 + tid;
  int c = (i < N) ? (int)(deg[i] + 0.5f) : 0;
  int val = c;
  for (int off = 1; off < 256; off <<= 1) {
    sh[tid] = val; __syncthreads();
    if (tid >= off) val += sh[tid - off];
    __syncthreads();
  }
  if (i < N) offs[i] = val - c;
  if (tid == 255) bsum[blockIdx.x] = val;
}

__global__ void scan_bsum_k(int* __restrict__ bsum, int nb) {
  __shared__ int sh[1024];
  int tid = threadIdx.x;
  int c = (tid < nb) ? bsum[tid] : 0;
  int val = c;
  for (int off = 1; off < 1024; off <<= 1) {
    sh[tid] = val; __syncthreads();
    if (tid >= off) val += sh[tid - off];
    __syncthreads();
  }
  if (tid < nb) bsum[tid] = val - c;
}

__global__ void scan_add_k(int* __restrict__ offs, const int* __restrict__ bsum,
                           int* __restrict__ gcur, float* __restrict__ inv,
                           const float* __restrict__ deg, int N, int E) {
  int i = blockIdx.x * 256 + threadIdx.x;
  if (i < N) {
    int o = offs[i] + bsum[i >> 8];
    offs[i] = o;
    inv[i] = rsqrtf(deg[i] + 1.0f);
    if ((i & 511) == 0) gcur[i >> 9] = o;   // bucket claim cursor = bucket base
  } else if (i == N) {
    offs[N] = E;
  }
}

// ---- phase C: bucket-scatter edges into (src,dst) pairs, bucket = dst>>9 ----
__global__ __launch_bounds__(256) void scatter_k(
    const int* __restrict__ src, const int* __restrict__ dst,
    int* __restrict__ gcur, uint2* __restrict__ pairs, int E) {
  __shared__ int hist[256];
  __shared__ int base_[256];
  const int tid = threadIdx.x;
  const int e0 = blockIdx.x * 8192;
  const int e1 = min(E, e0 + 8192);
  hist[tid] = 0;
  __syncthreads();
  for (int e = e0 + tid; e < e1; e += 256)
    atomicAdd(&hist[dst[e] >> 9], 1);
  __syncthreads();
  int c = hist[tid];
  if (c > 0) base_[tid] = atomicAdd(&gcur[tid], c);
  hist[tid] = 0;
  __syncthreads();
  for (int e = e0 + tid; e < e1; e += 256) {
    int d = dst[e];
    int b = d >> 9;
    int r = atomicAdd(&hist[b], 1);
    pairs[base_[b] + r] = make_uint2((u32)src[e], (u32)d);
  }
}

// ---- phase D: per-bucket CSR fill, cursors in LDS, col window L2-resident ----
__global__ __launch_bounds__(256) void fill2_k(
    const uint2* __restrict__ pairs, const int* __restrict__ offs,
    int* __restrict__ col, int N) {
  __shared__ int cur[512];
  const int b = blockIdx.x;
  const int n0 = b << 9;
  const int n1 = min(N, n0 + 512);
  const int tid = threadIdx.x;
  for (int i = tid; i < n1 - n0; i += 256) cur[i] = offs[n0 + i];
  __syncthreads();
  const int e0 = offs[n0], e1 = offs[n1];
  for (int e = e0 + tid; e < e1; e += 256) {
    uint2 pr = pairs[e];
    int p = atomicAdd(&cur[(int)pr.y - n0], 1);
    col[p] = (int)pr.x;
  }
}

// ---------------- SpMM (bf16): agg[d] = inv[d]*(msc[d] + sum msc[src]) -------
// 16 lanes x uint4 per row; 4 neighbor rows per wave iteration.
__global__ __launch_bounds__(256) void spmm_k(
    const uint4* __restrict__ msc, const int* __restrict__ offs,
    const int* __restrict__ col, const float* __restrict__ inv,
    uint4* __restrict__ agg, int N) {
  const int wid = threadIdx.x >> 6, lane = threadIdx.x & 63;
  const int d = blockIdx.x * 4 + wid;
  if (d >= N) return;
  const int g = lane >> 4, c = lane & 15;
  const int s0 = offs[d], s1 = offs[d + 1];
  float f0 = 0.f, f1 = 0.f, f2 = 0.f, f3 = 0.f, f4 = 0.f, f5 = 0.f, f6 = 0.f, f7 = 0.f;
  for (int base = s0; base < s1; base += 4) {
    int jj = base + g;
    bool v = jj < s1;
    int s = col[v ? jj : s0];
    uint4 r = msc[(size_t)s * 16 + c];
    if (v) {
      f0 += bflo(r.x); f1 += bfhi(r.x);
      f2 += bflo(r.y); f3 += bfhi(r.y);
      f4 += bflo(r.z); f5 += bfhi(r.z);
      f6 += bflo(r.w); f7 += bfhi(r.w);
    }
  }
  f0 += __shfl_xor(f0, 16, 64); f0 += __shfl_xor(f0, 32, 64);
  f1 += __shfl_xor(f1, 16, 64); f1 += __shfl_xor(f1, 32, 64);
  f2 += __shfl_xor(f2, 16, 64); f2 += __shfl_xor(f2, 32, 64);
  f3 += __shfl_xor(f3, 16, 64); f3 += __shfl_xor(f3, 32, 64);
  f4 += __shfl_xor(f4, 16, 64); f4 += __shfl_xor(f4, 32, 64);
  f5 += __shfl_xor(f5, 16, 64); f5 += __shfl_xor(f5, 32, 64);
  f6 += __shfl_xor(f6, 16, 64); f6 += __shfl_xor(f6, 32, 64);
  f7 += __shfl_xor(f7, 16, 64); f7 += __shfl_xor(f7, 32, 64);
  if (g == 0) {
    uint4 r = msc[(size_t)d * 16 + c];   // self loop
    float iv = inv[d];
    uint4 o;
    o.x = pack2((f0 + bflo(r.x)) * iv, (f1 + bfhi(r.x)) * iv);
    o.y = pack2((f2 + bflo(r.y)) * iv, (f3 + bfhi(r.y)) * iv);
    o.z = pack2((f4 + bflo(r.z)) * iv, (f5 + bfhi(r.z)) * iv);
    o.w = pack2((f6 + bflo(r.w)) * iv, (f7 + bfhi(r.w)) * iv);
    agg[(size_t)d * 16 + c] = o;
  }
}

// ---------------- weight pre-pack: fp32 [128][ncol] -> bf16 MFMA fragments ----
__global__ void pack_w_k(const float* __restrict__ W, u16* __restrict__ P, int ncol) {
  int t = blockIdx.x * 256 + threadIdx.x;
  int NT = ncol >> 4;
  int total = 4 * NT * 64;
  if (t >= total) return;
  int lane = t & 63;
  int tmp = t >> 6;
  int nt = tmp % NT, kc = tmp / NT;
  int n = nt * 16 + (lane & 15);
  int kb = kc * 32 + ((lane >> 4) << 2);
  u16* dst = P + (size_t)t * 8;
#pragma unroll
  for (int j = 0; j < 8; ++j) {
    int k = kb + (j & 3) + ((j >> 2) << 4);
    dst[j] = f2bf(W[(size_t)k * ncol + n]);
  }
}

// ---------------- MFMA GEMM: [N,128] @ [128,NOUT] + fused prep/epilogue ------
template <int NOUT, int PREP, int EPI>
__global__ __launch_bounds__(256) void gemm_mfma(
    const void* __restrict__ Xv, const u16* __restrict__ Wp,
    const float* __restrict__ bias, void* __restrict__ Yv,
    const float* __restrict__ res,
    const float* __restrict__ g1, const float* __restrict__ lb1,
    int N) {
  constexpr int NT = NOUT / 16;
  __shared__ union {
    u16  xs[32][136];
    float cs[32][132];
  } sh;
  const int tid = threadIdx.x;
  const int lane = tid & 63, wid = tid >> 6;
  const int row0 = blockIdx.x * 32;

  if constexpr (PREP == PREP_F32) {
    const float* X = (const float*)Xv;
    for (int i = tid; i < 1024; i += 256) {
      int r = i >> 5, c4 = i & 31;
      float4 v = ((const float4*)(X + (size_t)(row0 + r) * 128))[c4];
      u16x4 o = {f2bf(v.x), f2bf(v.y), f2bf(v.z), f2bf(v.w)};
      *(u16x4*)&sh.xs[r][c4 * 4] = o;
    }
  } else if constexpr (PREP == PREP_BF16) {
    const u16x4* X = (const u16x4*)Xv;
    for (int i = tid; i < 1024; i += 256) {
      int r = i >> 5, c4 = i & 31;
      *(u16x4*)&sh.xs[r][c4 * 4] = X[(size_t)(row0 + r) * 32 + c4];
    }
  } else {  // PREP_LN
    const float* X = (const float*)Xv;
    float2 gg = *(const float2*)&g1[lane * 2];
    float2 bb = *(const float2*)&lb1[lane * 2];
    for (int rr = 0; rr < 8; ++rr) {
      int r = wid * 8 + rr;
      float2 t = ((const float2*)(X + (size_t)(row0 + r) * 128))[lane];
      float mean = wred(t.x + t.y) * (1.f / 128.f);
      float dx = t.x - mean, dy = t.y - mean;
      float var = wred(dx * dx + dy * dy) * (1.f / 128.f);
      float rstd = rsqrtf(var + 1e-5f);
      u16x2 o = {f2bf(dx * rstd * gg.x + bb.x), f2bf(dy * rstd * gg.y + bb.y)};
      *(u16x2*)&sh.xs[r][lane * 2] = o;
    }
  }
  __syncthreads();

  constexpr int NTW = (NOUT == 128) ? 4 : 2;
  const int m0  = (NOUT == 128) ? ((wid >> 1) << 4) : ((wid & 1) << 4);
  const int ntb = (NOUT == 128) ? ((wid & 1) << 2) : ((wid >> 1) << 1);

  f32x4 acc[NTW];
#pragma unroll
  for (int t = 0; t < NTW; ++t) acc[t] = (f32x4){0.f, 0.f, 0.f, 0.f};

  const int ar  = m0 + (lane & 15);
  const int akb = (lane >> 4) << 2;
  const bf16x8* Bp = (const bf16x8*)Wp;
#pragma unroll
  for (int kc = 0; kc < 4; ++kc) {
    u16x4 lo = *(const u16x4*)&sh.xs[ar][kc * 32 + akb];
    u16x4 hi = *(const u16x4*)&sh.xs[ar][kc * 32 + akb + 16];
    u16x8 av;
#pragma unroll
    for (int j = 0; j < 4; ++j) { av[j] = lo[j]; av[j + 4] = hi[j]; }
    bf16x8 a = __builtin_bit_cast(bf16x8, av);
#pragma unroll
    for (int t = 0; t < NTW; ++t) {
      bf16x8 b = Bp[(kc * NT + ntb + t) * 64 + lane];
      acc[t] = __builtin_amdgcn_mfma_f32_16x16x32_bf16(a, b, acc[t], 0, 0, 0);
    }
  }

  const int cb = lane & 15;
  const int rg = (lane >> 4) << 2;
  if constexpr (EPI == EPI_IN) {
    float* Y = (float*)Yv;
#pragma unroll
    for (int t = 0; t < NTW; ++t) {
      int col = (ntb + t) * 16 + cb;
      float bv = bias[col];
#pragma unroll
      for (int r = 0; r < 4; ++r) {
        int gr = row0 + m0 + rg + r;
        Y[(size_t)gr * NOUT + col] = fmaxf(acc[t][r] + bv, 0.f);
      }
    }
  } else if constexpr (EPI == EPI_NONE) {
    float* Y = (float*)Yv;
#pragma unroll
    for (int t = 0; t < NTW; ++t) {
      int col = (ntb + t) * 16 + cb;
      float bv = bias[col];
#pragma unroll
      for (int r = 0; r < 4; ++r) {
        int gr = row0 + m0 + rg + r;
        Y[(size_t)gr * NOUT + col] = acc[t][r] + bv;
      }
    }
  } else if constexpr (EPI == EPI_SCALE) {
    u16* Y = (u16*)Yv;
#pragma unroll
    for (int t = 0; t < NTW; ++t) {
      int col = (ntb + t) * 16 + cb;
      float bv = bias[col];
#pragma unroll
      for (int r = 0; r < 4; ++r) {
        int gr = row0 + m0 + rg + r;
        Y[(size_t)gr * NOUT + col] = f2bf((acc[t][r] + bv) * res[gr]);
      }
    }
  } else {  // EPI_LNRES
    __syncthreads();
#pragma unroll
    for (int t = 0; t < NTW; ++t) {
      int col = (ntb + t) * 16 + cb;
      float bv = bias[col];
#pragma unroll
      for (int r = 0; r < 4; ++r) sh.cs[m0 + rg + r][col] = acc[t][r] + bv;
    }
    __syncthreads();
    float* Y = (float*)Yv;
    float2 gg = *(const float2*)&g1[lane * 2];
    float2 bb = *(const float2*)&lb1[lane * 2];
    for (int rr = 0; rr < 8; ++rr) {
      int r = wid * 8 + rr;
      int gr = row0 + r;
      float2 t2 = *(const float2*)&sh.cs[r][lane * 2];
      float2 h0 = ((const float2*)(res + (size_t)gr * 128))[lane];
      float tx = t2.x + h0.x, ty = t2.y + h0.y;
      float mean = wred(tx + ty) * (1.f / 128.f);
      float dx = tx - mean, dy = ty - mean;
      float var = wred(dx * dx + dy * dy) * (1.f / 128.f);
      float rstd = rsqrtf(var + 1e-5f);
      float y0 = fmaxf(dx * rstd * gg.x + bb.x, 0.f);
      float y1 = fmaxf(dy * rstd * gg.y + bb.y, 0.f);
      ((float2*)(Y + (size_t)gr * 128))[lane] = make_float2(y0, y1);
    }
  }
}

// ---------------------------------------------------------------------------
extern "C" void kernel_launch(void* const* d_in, const int* in_sizes, int n_in,
                              void* d_out, int out_size, void* d_ws, size_t ws_size,
                              hipStream_t stream) {
  (void)n_in; (void)out_size; (void)ws_size;
  const float* x      = (const float*)d_in[0];
  const int*   eidx   = (const int*)d_in[1];
  const float* degree = (const float*)d_in[2];
  const float* Win    = (const float*)d_in[3];
  const float* b_in   = (const float*)d_in[4];
  const float* W1     = (const float*)d_in[5];
  const float* b1     = (const float*)d_in[6];
  const float* W2     = (const float*)d_in[7];
  const float* b2     = (const float*)d_in[8];
  const float* ln_g   = (const float*)d_in[9];
  const float* ln_b   = (const float*)d_in[10];
  const float* out_g  = (const float*)d_in[11];
  const float* out_b  = (const float*)d_in[12];
  const float* Wout   = (const float*)d_in[13];
  const float* b_out  = (const float*)d_in[14];

  const int N = in_sizes[0] / 128;
  const int E = in_sizes[1] / 2;
  const int* esrc = eidx;
  const int* edst = eidx + E;

  char* p = (char*)d_ws;
  auto alloc = [&](size_t bytes) {
    char* q = p;
    p += (bytes + 255) & ~(size_t)255;
    return q;
  };
  float* inv    = (float*)alloc((size_t)N * 4);
  int*   offs   = (int*)alloc(((size_t)N + 1) * 4);
  int*   gcur   = (int*)alloc(256 * 4);
  int*   bsum   = (int*)alloc(1024 * 4);
  int*   col    = (int*)alloc((size_t)E * 4);
  uint2* pairs  = (uint2*)alloc((size_t)E * 8);
  float* h      = (float*)alloc((size_t)N * 128 * 4);
  u32*   msc    = (u32*)alloc((size_t)N * 128 * 2);
  u32*   agg    = (u32*)alloc((size_t)N * 128 * 2);
  u16*   pWin   = (u16*)alloc(4 * 8 * 64 * 8 * 2);
  u16*   pWout  = (u16*)alloc(4 * 4 * 64 * 8 * 2);
  u16*   pW1    = (u16*)alloc(3 * 4 * 8 * 64 * 8 * 2);
  u16*   pW2    = (u16*)alloc(3 * 4 * 8 * 64 * 8 * 2);

  pack_w_k<<<8, 256, 0, stream>>>(Win, pWin, 128);
  for (int l = 0; l < 3; ++l) {
    pack_w_k<<<8, 256, 0, stream>>>(W1 + (size_t)l * 128 * 128, pW1 + (size_t)l * 16384, 128);
    pack_w_k<<<8, 256, 0, stream>>>(W2 + (size_t)l * 128 * 128, pW2 + (size_t)l * 16384, 128);
  }
  pack_w_k<<<4, 256, 0, stream>>>(Wout, pWout, 64);

  const int nb = (N + 255) / 256;
  const int NB = (N + 511) / 512;              // dst buckets of 512 nodes
  scan_block_k<<<nb, 256, 0, stream>>>(degree, offs, bsum, N);
  scan_bsum_k<<<1, 1024, 0, stream>>>(bsum, nb);
  scan_add_k<<<(N + 256) / 256, 256, 0, stream>>>(offs, bsum, gcur, inv, degree, N, E);
  scatter_k<<<(E + 8191) / 8192, 256, 0, stream>>>(esrc, edst, gcur, pairs, E);
  fill2_k<<<NB, 256, 0, stream>>>(pairs, offs, col, N);

  const int gemmGrid = (N + 31) / 32;
  const int rowGrid  = (N + 3) / 4;

  gemm_mfma<128, PREP_F32, EPI_IN><<<gemmGrid, 256, 0, stream>>>(
      x, pWin, b_in, h, nullptr, nullptr, nullptr, N);
  for (int l = 0; l < 3; ++l) {
    gemm_mfma<128, PREP_F32, EPI_SCALE><<<gemmGrid, 256, 0, stream>>>(
        h, pW1 + (size_t)l * 16384, b1 + l * 128, msc, inv, nullptr, nullptr, N);
    spmm_k<<<rowGrid, 256, 0, stream>>>((const uint4*)msc, offs, col, inv, (uint4*)agg, N);
    gemm_mfma<128, PREP_BF16, EPI_LNRES><<<gemmGrid, 256, 0, stream>>>(
        agg, pW2 + (size_t)l * 16384, b2 + l * 128, h, h,
        ln_g + l * 128, ln_b + l * 128, N);
  }
  gemm_mfma<64, PREP_LN, EPI_NONE><<<gemmGrid, 256, 0, stream>>>(
      h, pWout, b_out, d_out, nullptr, out_g, out_b, N);
}

// Round 4
// 424.410 us; speedup vs baseline: 2.8477x; 1.0802x over previous
//
#include <hip/hip_runtime.h>
#include <cstdint>
#include <cstddef>

typedef unsigned short u16;
typedef unsigned int u32;
typedef __attribute__((ext_vector_type(2))) unsigned short u16x2;
typedef __attribute__((ext_vector_type(4))) unsigned short u16x4;
typedef __attribute__((ext_vector_type(8))) unsigned short u16x8;
typedef __attribute__((ext_vector_type(8))) __bf16 bf16x8;
typedef __attribute__((ext_vector_type(4))) float f32x4;

#define PREP_F32  0
#define PREP_BF16 1
#define PREP_LN   2
#define EPI_IN    0   // y = relu(xW + b)                -> fp32
#define EPI_SCALE 1   // y = inv[r]*(xW + b)             -> bf16
#define EPI_LNRES 2   // y = relu(LN(xW + b + res))      -> fp32 (in-place ok)
#define EPI_NONE  3   // y = xW + b                      -> fp32 (NOUT=64)

__device__ __forceinline__ float wred(float v) {
#pragma unroll
  for (int m = 32; m >= 1; m >>= 1) v += __shfl_xor(v, m, 64);
  return v;
}
__device__ __forceinline__ u16 f2bf(float f) {
  u32 u = __float_as_uint(f);
  u += 0x7fffu + ((u >> 16) & 1u);
  return (u16)(u >> 16);
}
__device__ __forceinline__ float bflo(u32 u) { return __uint_as_float(u << 16); }
__device__ __forceinline__ float bfhi(u32 u) { return __uint_as_float(u & 0xffff0000u); }
__device__ __forceinline__ u32 pack2(float a, float b) {
  u32 ua = __float_as_uint(a); ua += 0x7fffu + ((ua >> 16) & 1u);
  u32 ub = __float_as_uint(b); ub += 0x7fffu + ((ub >> 16) & 1u);
  return (ua >> 16) | (ub & 0xffff0000u);
}

// ---------------- CSR build: hierarchical exclusive scan of int(degree) ----
__global__ void scan_block_k(const float* __restrict__ deg, int* __restrict__ offs,
                             int* __restrict__ bsum, int N) {
  __shared__ int sh[256];
  int tid = threadIdx.x;
  int i = blockIdx.x * 256 + tid;
  int c = (i < N) ? (int)(deg[i] + 0.5f) : 0;
  int val = c;
  for (int off = 1; off < 256; off <<= 1) {
    sh[tid] = val; __syncthreads();
    if (tid >= off) val += sh[tid - off];
    __syncthreads();
  }
  if (i < N) offs[i] = val - c;
  if (tid == 255) bsum[blockIdx.x] = val;
}

__global__ void scan_bsum_k(int* __restrict__ bsum, int nb) {
  __shared__ int sh[1024];
  int tid = threadIdx.x;
  int c = (tid < nb) ? bsum[tid] : 0;
  int val = c;
  for (int off = 1; off < 1024; off <<= 1) {
    sh[tid] = val; __syncthreads();
    if (tid >= off) val += sh[tid - off];
    __syncthreads();
  }
  if (tid < nb) bsum[tid] = val - c;
}

__global__ void scan_add_k(int* __restrict__ offs, const int* __restrict__ bsum,
                           int* __restrict__ gcur, float* __restrict__ inv,
                           const float* __restrict__ deg, int N, int E) {
  int i = blockIdx.x * 256 + threadIdx.x;
  if (i < N) {
    int o = offs[i] + bsum[i >> 8];
    offs[i] = o;
    inv[i] = rsqrtf(deg[i] + 1.0f);
    if ((i & 511) == 0) gcur[i >> 9] = o;   // bucket claim cursor = bucket base
  } else if (i == N) {
    offs[N] = E;
  }
}

// ---- phase C: bucket-scatter edges into (src,dst) pairs, bucket = dst>>9 ----
__global__ __launch_bounds__(256) void scatter_k(
    const int* __restrict__ src, const int* __restrict__ dst,
    int* __restrict__ gcur, uint2* __restrict__ pairs, int E) {
  __shared__ int hist[256];
  __shared__ int base_[256];
  const int tid = threadIdx.x;
  const int e0 = blockIdx.x * 8192;
  const int e1 = min(E, e0 + 8192);
  hist[tid] = 0;
  __syncthreads();
  for (int e = e0 + tid; e < e1; e += 256)
    atomicAdd(&hist[dst[e] >> 9], 1);
  __syncthreads();
  int c = hist[tid];
  if (c > 0) base_[tid] = atomicAdd(&gcur[tid], c);
  hist[tid] = 0;
  __syncthreads();
  for (int e = e0 + tid; e < e1; e += 256) {
    int d = dst[e];
    int b = d >> 9;
    int r = atomicAdd(&hist[b], 1);
    pairs[base_[b] + r] = make_uint2((u32)src[e], (u32)d);
  }
}

// ---- phase D: per-bucket CSR fill, cursors in LDS, col window L2-resident ----
__global__ __launch_bounds__(256) void fill2_k(
    const uint2* __restrict__ pairs, const int* __restrict__ offs,
    int* __restrict__ col, int N) {
  __shared__ int cur[512];
  const int b = blockIdx.x;
  const int n0 = b << 9;
  const int n1 = min(N, n0 + 512);
  const int tid = threadIdx.x;
  for (int i = tid; i < n1 - n0; i += 256) cur[i] = offs[n0 + i];
  __syncthreads();
  const int e0 = offs[n0], e1 = offs[n1];
  for (int e = e0 + tid; e < e1; e += 256) {
    uint2 pr = pairs[e];
    int p = atomicAdd(&cur[(int)pr.y - n0], 1);
    col[p] = (int)pr.x;
  }
}

// ---------------- SpMM (bf16): agg[d] = inv[d]*(msc[d] + sum msc[src]) -------
// 16 lanes x uint4 per row; 16 neighbors per wave iteration (4 gathers in
// flight per lane -> MLP 4). OOB slots clamp to s1-1 (cache-hot re-read).
__global__ __launch_bounds__(256) void spmm_k(
    const uint4* __restrict__ msc, const int* __restrict__ offs,
    const int* __restrict__ col, const float* __restrict__ inv,
    uint4* __restrict__ agg, int N) {
  const int wid = threadIdx.x >> 6, lane = threadIdx.x & 63;
  const int d = blockIdx.x * 4 + wid;
  if (d >= N) return;
  const int g = lane >> 4, c = lane & 15;
  const int s0 = offs[d], s1 = offs[d + 1];
  float f0 = 0.f, f1 = 0.f, f2 = 0.f, f3 = 0.f, f4 = 0.f, f5 = 0.f, f6 = 0.f, f7 = 0.f;
  const int last = s1 - 1;
  for (int base = s0; base < s1; base += 16) {
    int jj0 = base + g;
    int jj1 = base + 4 + g;
    int jj2 = base + 8 + g;
    int jj3 = base + 12 + g;
    int sA = col[min(jj0, last)];
    int sB = col[min(jj1, last)];
    int sC = col[min(jj2, last)];
    int sD = col[min(jj3, last)];
    uint4 rA = msc[(size_t)sA * 16 + c];
    uint4 rB = msc[(size_t)sB * 16 + c];
    uint4 rC = msc[(size_t)sC * 16 + c];
    uint4 rD = msc[(size_t)sD * 16 + c];
    float mA = (jj0 <= last) ? 1.f : 0.f;
    float mB = (jj1 <= last) ? 1.f : 0.f;
    float mC = (jj2 <= last) ? 1.f : 0.f;
    float mD = (jj3 <= last) ? 1.f : 0.f;
    f0 = fmaf(mA, bflo(rA.x), f0); f1 = fmaf(mA, bfhi(rA.x), f1);
    f2 = fmaf(mA, bflo(rA.y), f2); f3 = fmaf(mA, bfhi(rA.y), f3);
    f4 = fmaf(mA, bflo(rA.z), f4); f5 = fmaf(mA, bfhi(rA.z), f5);
    f6 = fmaf(mA, bflo(rA.w), f6); f7 = fmaf(mA, bfhi(rA.w), f7);
    f0 = fmaf(mB, bflo(rB.x), f0); f1 = fmaf(mB, bfhi(rB.x), f1);
    f2 = fmaf(mB, bflo(rB.y), f2); f3 = fmaf(mB, bfhi(rB.y), f3);
    f4 = fmaf(mB, bflo(rB.z), f4); f5 = fmaf(mB, bfhi(rB.z), f5);
    f6 = fmaf(mB, bflo(rB.w), f6); f7 = fmaf(mB, bfhi(rB.w), f7);
    f0 = fmaf(mC, bflo(rC.x), f0); f1 = fmaf(mC, bfhi(rC.x), f1);
    f2 = fmaf(mC, bflo(rC.y), f2); f3 = fmaf(mC, bfhi(rC.y), f3);
    f4 = fmaf(mC, bflo(rC.z), f4); f5 = fmaf(mC, bfhi(rC.z), f5);
    f6 = fmaf(mC, bflo(rC.w), f6); f7 = fmaf(mC, bfhi(rC.w), f7);
    f0 = fmaf(mD, bflo(rD.x), f0); f1 = fmaf(mD, bfhi(rD.x), f1);
    f2 = fmaf(mD, bflo(rD.y), f2); f3 = fmaf(mD, bfhi(rD.y), f3);
    f4 = fmaf(mD, bflo(rD.z), f4); f5 = fmaf(mD, bfhi(rD.z), f5);
    f6 = fmaf(mD, bflo(rD.w), f6); f7 = fmaf(mD, bfhi(rD.w), f7);
  }
  f0 += __shfl_xor(f0, 16, 64); f0 += __shfl_xor(f0, 32, 64);
  f1 += __shfl_xor(f1, 16, 64); f1 += __shfl_xor(f1, 32, 64);
  f2 += __shfl_xor(f2, 16, 64); f2 += __shfl_xor(f2, 32, 64);
  f3 += __shfl_xor(f3, 16, 64); f3 += __shfl_xor(f3, 32, 64);
  f4 += __shfl_xor(f4, 16, 64); f4 += __shfl_xor(f4, 32, 64);
  f5 += __shfl_xor(f5, 16, 64); f5 += __shfl_xor(f5, 32, 64);
  f6 += __shfl_xor(f6, 16, 64); f6 += __shfl_xor(f6, 32, 64);
  f7 += __shfl_xor(f7, 16, 64); f7 += __shfl_xor(f7, 32, 64);
  if (g == 0) {
    uint4 r = msc[(size_t)d * 16 + c];   // self loop
    float iv = inv[d];
    uint4 o;
    o.x = pack2((f0 + bflo(r.x)) * iv, (f1 + bfhi(r.x)) * iv);
    o.y = pack2((f2 + bflo(r.y)) * iv, (f3 + bfhi(r.y)) * iv);
    o.z = pack2((f4 + bflo(r.z)) * iv, (f5 + bfhi(r.z)) * iv);
    o.w = pack2((f6 + bflo(r.w)) * iv, (f7 + bfhi(r.w)) * iv);
    agg[(size_t)d * 16 + c] = o;
  }
}

// ---------------- weight pre-pack: fp32 [128][ncol] -> bf16 MFMA fragments ----
__global__ void pack_w_k(const float* __restrict__ W, u16* __restrict__ P, int ncol) {
  int t = blockIdx.x * 256 + threadIdx.x;
  int NT = ncol >> 4;
  int total = 4 * NT * 64;
  if (t >= total) return;
  int lane = t & 63;
  int tmp = t >> 6;
  int nt = tmp % NT, kc = tmp / NT;
  int n = nt * 16 + (lane & 15);
  int kb = kc * 32 + ((lane >> 4) << 2);
  u16* dst = P + (size_t)t * 8;
#pragma unroll
  for (int j = 0; j < 8; ++j) {
    int k = kb + (j & 3) + ((j >> 2) << 4);
    dst[j] = f2bf(W[(size_t)k * ncol + n]);
  }
}

// ---------------- MFMA GEMM: [N,128] @ [128,NOUT] + fused prep/epilogue ------
template <int NOUT, int PREP, int EPI>
__global__ __launch_bounds__(256) void gemm_mfma(
    const void* __restrict__ Xv, const u16* __restrict__ Wp,
    const float* __restrict__ bias, void* __restrict__ Yv,
    const float* __restrict__ res,
    const float* __restrict__ g1, const float* __restrict__ lb1,
    int N) {
  constexpr int NT = NOUT / 16;
  __shared__ union {
    u16  xs[32][136];
    float cs[32][132];
  } sh;
  const int tid = threadIdx.x;
  const int lane = tid & 63, wid = tid >> 6;
  const int row0 = blockIdx.x * 32;

  if constexpr (PREP == PREP_F32) {
    const float* X = (const float*)Xv;
    for (int i = tid; i < 1024; i += 256) {
      int r = i >> 5, c4 = i & 31;
      float4 v = ((const float4*)(X + (size_t)(row0 + r) * 128))[c4];
      u16x4 o = {f2bf(v.x), f2bf(v.y), f2bf(v.z), f2bf(v.w)};
      *(u16x4*)&sh.xs[r][c4 * 4] = o;
    }
  } else if constexpr (PREP == PREP_BF16) {
    const u16x4* X = (const u16x4*)Xv;
    for (int i = tid; i < 1024; i += 256) {
      int r = i >> 5, c4 = i & 31;
      *(u16x4*)&sh.xs[r][c4 * 4] = X[(size_t)(row0 + r) * 32 + c4];
    }
  } else {  // PREP_LN
    const float* X = (const float*)Xv;
    float2 gg = *(const float2*)&g1[lane * 2];
    float2 bb = *(const float2*)&lb1[lane * 2];
    for (int rr = 0; rr < 8; ++rr) {
      int r = wid * 8 + rr;
      float2 t = ((const float2*)(X + (size_t)(row0 + r) * 128))[lane];
      float mean = wred(t.x + t.y) * (1.f / 128.f);
      float dx = t.x - mean, dy = t.y - mean;
      float var = wred(dx * dx + dy * dy) * (1.f / 128.f);
      float rstd = rsqrtf(var + 1e-5f);
      u16x2 o = {f2bf(dx * rstd * gg.x + bb.x), f2bf(dy * rstd * gg.y + bb.y)};
      *(u16x2*)&sh.xs[r][lane * 2] = o;
    }
  }
  __syncthreads();

  constexpr int NTW = (NOUT == 128) ? 4 : 2;
  const int m0  = (NOUT == 128) ? ((wid >> 1) << 4) : ((wid & 1) << 4);
  const int ntb = (NOUT == 128) ? ((wid & 1) << 2) : ((wid >> 1) << 1);

  f32x4 acc[NTW];
#pragma unroll
  for (int t = 0; t < NTW; ++t) acc[t] = (f32x4){0.f, 0.f, 0.f, 0.f};

  const int ar  = m0 + (lane & 15);
  const int akb = (lane >> 4) << 2;
  const bf16x8* Bp = (const bf16x8*)Wp;
#pragma unroll
  for (int kc = 0; kc < 4; ++kc) {
    u16x4 lo = *(const u16x4*)&sh.xs[ar][kc * 32 + akb];
    u16x4 hi = *(const u16x4*)&sh.xs[ar][kc * 32 + akb + 16];
    u16x8 av;
#pragma unroll
    for (int j = 0; j < 4; ++j) { av[j] = lo[j]; av[j + 4] = hi[j]; }
    bf16x8 a = __builtin_bit_cast(bf16x8, av);
#pragma unroll
    for (int t = 0; t < NTW; ++t) {
      bf16x8 b = Bp[(kc * NT + ntb + t) * 64 + lane];
      acc[t] = __builtin_amdgcn_mfma_f32_16x16x32_bf16(a, b, acc[t], 0, 0, 0);
    }
  }

  const int cb = lane & 15;
  const int rg = (lane >> 4) << 2;
  if constexpr (EPI == EPI_IN) {
    float* Y = (float*)Yv;
#pragma unroll
    for (int t = 0; t < NTW; ++t) {
      int col = (ntb + t) * 16 + cb;
      float bv = bias[col];
#pragma unroll
      for (int r = 0; r < 4; ++r) {
        int gr = row0 + m0 + rg + r;
        Y[(size_t)gr * NOUT + col] = fmaxf(acc[t][r] + bv, 0.f);
      }
    }
  } else if constexpr (EPI == EPI_NONE) {
    float* Y = (float*)Yv;
#pragma unroll
    for (int t = 0; t < NTW; ++t) {
      int col = (ntb + t) * 16 + cb;
      float bv = bias[col];
#pragma unroll
      for (int r = 0; r < 4; ++r) {
        int gr = row0 + m0 + rg + r;
        Y[(size_t)gr * NOUT + col] = acc[t][r] + bv;
      }
    }
  } else if constexpr (EPI == EPI_SCALE) {
    u16* Y = (u16*)Yv;
#pragma unroll
    for (int t = 0; t < NTW; ++t) {
      int col = (ntb + t) * 16 + cb;
      float bv = bias[col];
#pragma unroll
      for (int r = 0; r < 4; ++r) {
        int gr = row0 + m0 + rg + r;
        Y[(size_t)gr * NOUT + col] = f2bf((acc[t][r] + bv) * res[gr]);
      }
    }
  } else {  // EPI_LNRES
    __syncthreads();
#pragma unroll
    for (int t = 0; t < NTW; ++t) {
      int col = (ntb + t) * 16 + cb;
      float bv = bias[col];
#pragma unroll
      for (int r = 0; r < 4; ++r) sh.cs[m0 + rg + r][col] = acc[t][r] + bv;
    }
    __syncthreads();
    float* Y = (float*)Yv;
    float2 gg = *(const float2*)&g1[lane * 2];
    float2 bb = *(const float2*)&lb1[lane * 2];
    for (int rr = 0; rr < 8; ++rr) {
      int r = wid * 8 + rr;
      int gr = row0 + r;
      float2 t2 = *(const float2*)&sh.cs[r][lane * 2];
      float2 h0 = ((const float2*)(res + (size_t)gr * 128))[lane];
      float tx = t2.x + h0.x, ty = t2.y + h0.y;
      float mean = wred(tx + ty) * (1.f / 128.f);
      float dx = tx - mean, dy = ty - mean;
      float var = wred(dx * dx + dy * dy) * (1.f / 128.f);
      float rstd = rsqrtf(var + 1e-5f);
      float y0 = fmaxf(dx * rstd * gg.x + bb.x, 0.f);
      float y1 = fmaxf(dy * rstd * gg.y + bb.y, 0.f);
      ((float2*)(Y + (size_t)gr * 128))[lane] = make_float2(y0, y1);
    }
  }
}

// ---------------------------------------------------------------------------
extern "C" void kernel_launch(void* const* d_in, const int* in_sizes, int n_in,
                              void* d_out, int out_size, void* d_ws, size_t ws_size,
                              hipStream_t stream) {
  (void)n_in; (void)out_size; (void)ws_size;
  const float* x      = (const float*)d_in[0];
  const int*   eidx   = (const int*)d_in[1];
  const float* degree = (const float*)d_in[2];
  const float* Win    = (const float*)d_in[3];
  const float* b_in   = (const float*)d_in[4];
  const float* W1     = (const float*)d_in[5];
  const float* b1     = (const float*)d_in[6];
  const float* W2     = (const float*)d_in[7];
  const float* b2     = (const float*)d_in[8];
  const float* ln_g   = (const float*)d_in[9];
  const float* ln_b   = (const float*)d_in[10];
  const float* out_g  = (const float*)d_in[11];
  const float* out_b  = (const float*)d_in[12];
  const float* Wout   = (const float*)d_in[13];
  const float* b_out  = (const float*)d_in[14];

  const int N = in_sizes[0] / 128;
  const int E = in_sizes[1] / 2;
  const int* esrc = eidx;
  const int* edst = eidx + E;

  char* p = (char*)d_ws;
  auto alloc = [&](size_t bytes) {
    char* q = p;
    p += (bytes + 255) & ~(size_t)255;
    return q;
  };
  float* inv    = (float*)alloc((size_t)N * 4);
  int*   offs   = (int*)alloc(((size_t)N + 1) * 4);
  int*   gcur   = (int*)alloc(256 * 4);
  int*   bsum   = (int*)alloc(1024 * 4);
  int*   col    = (int*)alloc((size_t)E * 4);
  uint2* pairs  = (uint2*)alloc((size_t)E * 8);
  float* h      = (float*)alloc((size_t)N * 128 * 4);
  u32*   msc    = (u32*)alloc((size_t)N * 128 * 2);
  u32*   agg    = (u32*)alloc((size_t)N * 128 * 2);
  u16*   pWin   = (u16*)alloc(4 * 8 * 64 * 8 * 2);
  u16*   pWout  = (u16*)alloc(4 * 4 * 64 * 8 * 2);
  u16*   pW1    = (u16*)alloc(3 * 4 * 8 * 64 * 8 * 2);
  u16*   pW2    = (u16*)alloc(3 * 4 * 8 * 64 * 8 * 2);

  pack_w_k<<<8, 256, 0, stream>>>(Win, pWin, 128);
  for (int l = 0; l < 3; ++l) {
    pack_w_k<<<8, 256, 0, stream>>>(W1 + (size_t)l * 128 * 128, pW1 + (size_t)l * 16384, 128);
    pack_w_k<<<8, 256, 0, stream>>>(W2 + (size_t)l * 128 * 128, pW2 + (size_t)l * 16384, 128);
  }
  pack_w_k<<<4, 256, 0, stream>>>(Wout, pWout, 64);

  const int nb = (N + 255) / 256;
  const int NB = (N + 511) / 512;              // dst buckets of 512 nodes
  scan_block_k<<<nb, 256, 0, stream>>>(degree, offs, bsum, N);
  scan_bsum_k<<<1, 1024, 0, stream>>>(bsum, nb);
  scan_add_k<<<(N + 256) / 256, 256, 0, stream>>>(offs, bsum, gcur, inv, degree, N, E);
  scatter_k<<<(E + 8191) / 8192, 256, 0, stream>>>(esrc, edst, gcur, pairs, E);
  fill2_k<<<NB, 256, 0, stream>>>(pairs, offs, col, N);

  const int gemmGrid = (N + 31) / 32;
  const int rowGrid  = (N + 3) / 4;

  gemm_mfma<128, PREP_F32, EPI_IN><<<gemmGrid, 256, 0, stream>>>(
      x, pWin, b_in, h, nullptr, nullptr, nullptr, N);
  for (int l = 0; l < 3; ++l) {
    gemm_mfma<128, PREP_F32, EPI_SCALE><<<gemmGrid, 256, 0, stream>>>(
        h, pW1 + (size_t)l * 16384, b1 + l * 128, msc, inv, nullptr, nullptr, N);
    spmm_k<<<rowGrid, 256, 0, stream>>>((const uint4*)msc, offs, col, inv, (uint4*)agg, N);
    gemm_mfma<128, PREP_BF16, EPI_LNRES><<<gemmGrid, 256, 0, stream>>>(
        agg, pW2 + (size_t)l * 16384, b2 + l * 128, h, h,
        ln_g + l * 128, ln_b + l * 128, N);
  }
  gemm_mfma<64, PREP_LN, EPI_NONE><<<gemmGrid, 256, 0, stream>>>(
      h, pWout, b_out, d_out, nullptr, out_g, out_b, N);
}

// Round 5
// 411.779 us; speedup vs baseline: 2.9351x; 1.0307x over previous
//
#include <hip/hip_runtime.h>
#include <cstdint>
#include <cstddef>

typedef unsigned short u16;
typedef unsigned int u32;
typedef __attribute__((ext_vector_type(2))) unsigned short u16x2;
typedef __attribute__((ext_vector_type(4))) unsigned short u16x4;
typedef __attribute__((ext_vector_type(8))) unsigned short u16x8;
typedef __attribute__((ext_vector_type(8))) __bf16 bf16x8;
typedef __attribute__((ext_vector_type(4))) float f32x4;

#define PREP_F32  0
#define PREP_BF16 1
#define PREP_LN   2
#define EPI_IN    0   // y = relu(xW + b)                -> bf16
#define EPI_SCALE 1   // y = inv[r]*(xW + b)             -> bf16
#define EPI_LNRES 2   // y = relu(LN(xW + b + res))      -> bf16 (in-place ok)
#define EPI_NONE  3   // y = xW + b                      -> fp32 (NOUT=64)

__device__ __forceinline__ float wred(float v) {
#pragma unroll
  for (int m = 32; m >= 1; m >>= 1) v += __shfl_xor(v, m, 64);
  return v;
}
__device__ __forceinline__ u16 f2bf(float f) {
  u32 u = __float_as_uint(f);
  u += 0x7fffu + ((u >> 16) & 1u);
  return (u16)(u >> 16);
}
__device__ __forceinline__ float bflo(u32 u) { return __uint_as_float(u << 16); }
__device__ __forceinline__ float bfhi(u32 u) { return __uint_as_float(u & 0xffff0000u); }
__device__ __forceinline__ u32 pack2(float a, float b) {
  u32 ua = __float_as_uint(a); ua += 0x7fffu + ((ua >> 16) & 1u);
  u32 ub = __float_as_uint(b); ub += 0x7fffu + ((ub >> 16) & 1u);
  return (ua >> 16) | (ub & 0xffff0000u);
}

// ---------------- CSR build: hierarchical exclusive scan of int(degree) ----
__global__ void scan_block_k(const float* __restrict__ deg, int* __restrict__ offs,
                             int* __restrict__ bsum, int N) {
  __shared__ int sh[256];
  int tid = threadIdx.x;
  int i = blockIdx.x * 256 + tid;
  int c = (i < N) ? (int)(deg[i] + 0.5f) : 0;
  int val = c;
  for (int off = 1; off < 256; off <<= 1) {
    sh[tid] = val; __syncthreads();
    if (tid >= off) val += sh[tid - off];
    __syncthreads();
  }
  if (i < N) offs[i] = val - c;
  if (tid == 255) bsum[blockIdx.x] = val;
}

__global__ void scan_bsum_k(int* __restrict__ bsum, int nb) {
  __shared__ int sh[1024];
  int tid = threadIdx.x;
  int c = (tid < nb) ? bsum[tid] : 0;
  int val = c;
  for (int off = 1; off < 1024; off <<= 1) {
    sh[tid] = val; __syncthreads();
    if (tid >= off) val += sh[tid - off];
    __syncthreads();
  }
  if (tid < nb) bsum[tid] = val - c;
}

__global__ void scan_add_k(int* __restrict__ offs, const int* __restrict__ bsum,
                           int* __restrict__ gcur, float* __restrict__ inv,
                           const float* __restrict__ deg, int N, int E) {
  int i = blockIdx.x * 256 + threadIdx.x;
  if (i < N) {
    int o = offs[i] + bsum[i >> 8];
    offs[i] = o;
    inv[i] = rsqrtf(deg[i] + 1.0f);
    if ((i & 511) == 0) gcur[i >> 9] = o;   // bucket claim cursor = bucket base
  } else if (i == N) {
    offs[N] = E;
  }
}

// ---- phase C: bucket-scatter edges into (src,dst) pairs, bucket = dst>>9 ----
__global__ __launch_bounds__(256) void scatter_k(
    const int* __restrict__ src, const int* __restrict__ dst,
    int* __restrict__ gcur, uint2* __restrict__ pairs, int E) {
  __shared__ int hist[256];
  __shared__ int base_[256];
  const int tid = threadIdx.x;
  const int e0 = blockIdx.x * 8192;
  const int e1 = min(E, e0 + 8192);
  hist[tid] = 0;
  __syncthreads();
  for (int e = e0 + tid; e < e1; e += 256)
    atomicAdd(&hist[dst[e] >> 9], 1);
  __syncthreads();
  int c = hist[tid];
  if (c > 0) base_[tid] = atomicAdd(&gcur[tid], c);
  hist[tid] = 0;
  __syncthreads();
  for (int e = e0 + tid; e < e1; e += 256) {
    int d = dst[e];
    int b = d >> 9;
    int r = atomicAdd(&hist[b], 1);
    pairs[base_[b] + r] = make_uint2((u32)src[e], (u32)d);
  }
}

// ---- phase D: per-bucket CSR fill, cursors in LDS, col window L2-resident ----
__global__ __launch_bounds__(256) void fill2_k(
    const uint2* __restrict__ pairs, const int* __restrict__ offs,
    int* __restrict__ col, int N) {
  __shared__ int cur[512];
  const int b = blockIdx.x;
  const int n0 = b << 9;
  const int n1 = min(N, n0 + 512);
  const int tid = threadIdx.x;
  for (int i = tid; i < n1 - n0; i += 256) cur[i] = offs[n0 + i];
  __syncthreads();
  const int e0 = offs[n0], e1 = offs[n1];
  for (int e = e0 + tid; e < e1; e += 256) {
    uint2 pr = pairs[e];
    int p = atomicAdd(&cur[(int)pr.y - n0], 1);
    col[p] = (int)pr.x;
  }
}

// ---------------- SpMM (bf16): agg[d] = inv[d]*(msc[d] + sum msc[src]) -------
// 16 lanes x uint4 per row; 16 neighbors per wave iteration (MLP 4/lane).
// Main loop unmasked over full 16-blocks; one masked tail iteration.
__global__ __launch_bounds__(256) void spmm_k(
    const uint4* __restrict__ msc, const int* __restrict__ offs,
    const int* __restrict__ col, const float* __restrict__ inv,
    uint4* __restrict__ agg, int N) {
  const int wid = threadIdx.x >> 6, lane = threadIdx.x & 63;
  const int d = blockIdx.x * 4 + wid;
  if (d >= N) return;
  const int g = lane >> 4, c = lane & 15;
  const int s0 = offs[d], s1 = offs[d + 1];
  float2 a0 = {0.f, 0.f}, a1 = {0.f, 0.f}, a2 = {0.f, 0.f}, a3 = {0.f, 0.f};
  int base = s0;
  const int nfull = s0 + ((s1 - s0) & ~15);
  for (; base < nfull; base += 16) {
    int sA = col[base + g];
    int sB = col[base + 4 + g];
    int sC = col[base + 8 + g];
    int sD = col[base + 12 + g];
    uint4 rA = msc[(size_t)sA * 16 + c];
    uint4 rB = msc[(size_t)sB * 16 + c];
    uint4 rC = msc[(size_t)sC * 16 + c];
    uint4 rD = msc[(size_t)sD * 16 + c];
    a0.x += bflo(rA.x); a0.y += bfhi(rA.x);
    a1.x += bflo(rA.y); a1.y += bfhi(rA.y);
    a2.x += bflo(rA.z); a2.y += bfhi(rA.z);
    a3.x += bflo(rA.w); a3.y += bfhi(rA.w);
    a0.x += bflo(rB.x); a0.y += bfhi(rB.x);
    a1.x += bflo(rB.y); a1.y += bfhi(rB.y);
    a2.x += bflo(rB.z); a2.y += bfhi(rB.z);
    a3.x += bflo(rB.w); a3.y += bfhi(rB.w);
    a0.x += bflo(rC.x); a0.y += bfhi(rC.x);
    a1.x += bflo(rC.y); a1.y += bfhi(rC.y);
    a2.x += bflo(rC.z); a2.y += bfhi(rC.z);
    a3.x += bflo(rC.w); a3.y += bfhi(rC.w);
    a0.x += bflo(rD.x); a0.y += bfhi(rD.x);
    a1.x += bflo(rD.y); a1.y += bfhi(rD.y);
    a2.x += bflo(rD.z); a2.y += bfhi(rD.z);
    a3.x += bflo(rD.w); a3.y += bfhi(rD.w);
  }
  if (base < s1) {
    const int last = s1 - 1;
    int jj0 = base + g;
    int jj1 = base + 4 + g;
    int jj2 = base + 8 + g;
    int jj3 = base + 12 + g;
    int sA = col[min(jj0, last)];
    int sB = col[min(jj1, last)];
    int sC = col[min(jj2, last)];
    int sD = col[min(jj3, last)];
    uint4 rA = msc[(size_t)sA * 16 + c];
    uint4 rB = msc[(size_t)sB * 16 + c];
    uint4 rC = msc[(size_t)sC * 16 + c];
    uint4 rD = msc[(size_t)sD * 16 + c];
    float mA = (jj0 <= last) ? 1.f : 0.f;
    float mB = (jj1 <= last) ? 1.f : 0.f;
    float mC = (jj2 <= last) ? 1.f : 0.f;
    float mD = (jj3 <= last) ? 1.f : 0.f;
    a0.x = fmaf(mA, bflo(rA.x), a0.x); a0.y = fmaf(mA, bfhi(rA.x), a0.y);
    a1.x = fmaf(mA, bflo(rA.y), a1.x); a1.y = fmaf(mA, bfhi(rA.y), a1.y);
    a2.x = fmaf(mA, bflo(rA.z), a2.x); a2.y = fmaf(mA, bfhi(rA.z), a2.y);
    a3.x = fmaf(mA, bflo(rA.w), a3.x); a3.y = fmaf(mA, bfhi(rA.w), a3.y);
    a0.x = fmaf(mB, bflo(rB.x), a0.x); a0.y = fmaf(mB, bfhi(rB.x), a0.y);
    a1.x = fmaf(mB, bflo(rB.y), a1.x); a1.y = fmaf(mB, bfhi(rB.y), a1.y);
    a2.x = fmaf(mB, bflo(rB.z), a2.x); a2.y = fmaf(mB, bfhi(rB.z), a2.y);
    a3.x = fmaf(mB, bflo(rB.w), a3.x); a3.y = fmaf(mB, bfhi(rB.w), a3.y);
    a0.x = fmaf(mC, bflo(rC.x), a0.x); a0.y = fmaf(mC, bfhi(rC.x), a0.y);
    a1.x = fmaf(mC, bflo(rC.y), a1.x); a1.y = fmaf(mC, bfhi(rC.y), a1.y);
    a2.x = fmaf(mC, bflo(rC.z), a2.x); a2.y = fmaf(mC, bfhi(rC.z), a2.y);
    a3.x = fmaf(mC, bflo(rC.w), a3.x); a3.y = fmaf(mC, bfhi(rC.w), a3.y);
    a0.x = fmaf(mD, bflo(rD.x), a0.x); a0.y = fmaf(mD, bfhi(rD.x), a0.y);
    a1.x = fmaf(mD, bflo(rD.y), a1.x); a1.y = fmaf(mD, bfhi(rD.y), a1.y);
    a2.x = fmaf(mD, bflo(rD.z), a2.x); a2.y = fmaf(mD, bfhi(rD.z), a2.y);
    a3.x = fmaf(mD, bflo(rD.w), a3.x); a3.y = fmaf(mD, bfhi(rD.w), a3.y);
  }
  a0.x += __shfl_xor(a0.x, 16, 64); a0.x += __shfl_xor(a0.x, 32, 64);
  a0.y += __shfl_xor(a0.y, 16, 64); a0.y += __shfl_xor(a0.y, 32, 64);
  a1.x += __shfl_xor(a1.x, 16, 64); a1.x += __shfl_xor(a1.x, 32, 64);
  a1.y += __shfl_xor(a1.y, 16, 64); a1.y += __shfl_xor(a1.y, 32, 64);
  a2.x += __shfl_xor(a2.x, 16, 64); a2.x += __shfl_xor(a2.x, 32, 64);
  a2.y += __shfl_xor(a2.y, 16, 64); a2.y += __shfl_xor(a2.y, 32, 64);
  a3.x += __shfl_xor(a3.x, 16, 64); a3.x += __shfl_xor(a3.x, 32, 64);
  a3.y += __shfl_xor(a3.y, 16, 64); a3.y += __shfl_xor(a3.y, 32, 64);
  if (g == 0) {
    uint4 r = msc[(size_t)d * 16 + c];   // self loop
    float iv = inv[d];
    uint4 o;
    o.x = pack2((a0.x + bflo(r.x)) * iv, (a0.y + bfhi(r.x)) * iv);
    o.y = pack2((a1.x + bflo(r.y)) * iv, (a1.y + bfhi(r.y)) * iv);
    o.z = pack2((a2.x + bflo(r.z)) * iv, (a2.y + bfhi(r.z)) * iv);
    o.w = pack2((a3.x + bflo(r.w)) * iv, (a3.y + bfhi(r.w)) * iv);
    agg[(size_t)d * 16 + c] = o;
  }
}

// ---------------- weight pre-pack: fp32 [128][ncol] -> bf16 MFMA fragments ----
__global__ void pack_w_k(const float* __restrict__ W, u16* __restrict__ P, int ncol) {
  int t = blockIdx.x * 256 + threadIdx.x;
  int NT = ncol >> 4;
  int total = 4 * NT * 64;
  if (t >= total) return;
  int lane = t & 63;
  int tmp = t >> 6;
  int nt = tmp % NT, kc = tmp / NT;
  int n = nt * 16 + (lane & 15);
  int kb = kc * 32 + ((lane >> 4) << 2);
  u16* dst = P + (size_t)t * 8;
#pragma unroll
  for (int j = 0; j < 8; ++j) {
    int k = kb + (j & 3) + ((j >> 2) << 4);
    dst[j] = f2bf(W[(size_t)k * ncol + n]);
  }
}

// ---------------- MFMA GEMM: [N,128] @ [128,NOUT] + fused prep/epilogue ------
template <int NOUT, int PREP, int EPI>
__global__ __launch_bounds__(256) void gemm_mfma(
    const void* __restrict__ Xv, const u16* __restrict__ Wp,
    const float* __restrict__ bias, void* __restrict__ Yv,
    const void* __restrict__ resv,   // inv fp32 (SCALE) or bf16 residual h (LNRES)
    const float* __restrict__ g1, const float* __restrict__ lb1,
    int N) {
  constexpr int NT = NOUT / 16;
  __shared__ union {
    u16  xs[32][136];
    float cs[32][132];
  } sh;
  const int tid = threadIdx.x;
  const int lane = tid & 63, wid = tid >> 6;
  const int row0 = blockIdx.x * 32;

  if constexpr (PREP == PREP_F32) {
    const float* X = (const float*)Xv;
    for (int i = tid; i < 1024; i += 256) {
      int r = i >> 5, c4 = i & 31;
      float4 v = ((const float4*)(X + (size_t)(row0 + r) * 128))[c4];
      u16x4 o = {f2bf(v.x), f2bf(v.y), f2bf(v.z), f2bf(v.w)};
      *(u16x4*)&sh.xs[r][c4 * 4] = o;
    }
  } else if constexpr (PREP == PREP_BF16) {
    const u16x4* X = (const u16x4*)Xv;
    for (int i = tid; i < 1024; i += 256) {
      int r = i >> 5, c4 = i & 31;
      *(u16x4*)&sh.xs[r][c4 * 4] = X[(size_t)(row0 + r) * 32 + c4];
    }
  } else {  // PREP_LN: normalize bf16 rows with g1/lb1
    const u32* X = (const u32*)Xv;
    float2 gg = *(const float2*)&g1[lane * 2];
    float2 bb = *(const float2*)&lb1[lane * 2];
    for (int rr = 0; rr < 8; ++rr) {
      int r = wid * 8 + rr;
      u32 v = X[(size_t)(row0 + r) * 64 + lane];
      float tx = bflo(v), ty = bfhi(v);
      float mean = wred(tx + ty) * (1.f / 128.f);
      float dx = tx - mean, dy = ty - mean;
      float var = wred(dx * dx + dy * dy) * (1.f / 128.f);
      float rstd = rsqrtf(var + 1e-5f);
      u16x2 o = {f2bf(dx * rstd * gg.x + bb.x), f2bf(dy * rstd * gg.y + bb.y)};
      *(u16x2*)&sh.xs[r][lane * 2] = o;
    }
  }
  __syncthreads();

  constexpr int NTW = (NOUT == 128) ? 4 : 2;
  const int m0  = (NOUT == 128) ? ((wid >> 1) << 4) : ((wid & 1) << 4);
  const int ntb = (NOUT == 128) ? ((wid & 1) << 2) : ((wid >> 1) << 1);

  f32x4 acc[NTW];
#pragma unroll
  for (int t = 0; t < NTW; ++t) acc[t] = (f32x4){0.f, 0.f, 0.f, 0.f};

  const int ar  = m0 + (lane & 15);
  const int akb = (lane >> 4) << 2;
  const bf16x8* Bp = (const bf16x8*)Wp;
#pragma unroll
  for (int kc = 0; kc < 4; ++kc) {
    u16x4 lo = *(const u16x4*)&sh.xs[ar][kc * 32 + akb];
    u16x4 hi = *(const u16x4*)&sh.xs[ar][kc * 32 + akb + 16];
    u16x8 av;
#pragma unroll
    for (int j = 0; j < 4; ++j) { av[j] = lo[j]; av[j + 4] = hi[j]; }
    bf16x8 a = __builtin_bit_cast(bf16x8, av);
#pragma unroll
    for (int t = 0; t < NTW; ++t) {
      bf16x8 b = Bp[(kc * NT + ntb + t) * 64 + lane];
      acc[t] = __builtin_amdgcn_mfma_f32_16x16x32_bf16(a, b, acc[t], 0, 0, 0);
    }
  }

  const int cb = lane & 15;
  const int rg = (lane >> 4) << 2;
  if constexpr (EPI == EPI_NONE) {
    float* Y = (float*)Yv;
#pragma unroll
    for (int t = 0; t < NTW; ++t) {
      int col = (ntb + t) * 16 + cb;
      float bv = bias[col];
#pragma unroll
      for (int r = 0; r < 4; ++r) {
        int gr = row0 + m0 + rg + r;
        Y[(size_t)gr * NOUT + col] = acc[t][r] + bv;
      }
    }
  } else if constexpr (EPI == EPI_SCALE) {
    const float* inv = (const float*)resv;
    u16* Y = (u16*)Yv;
#pragma unroll
    for (int t = 0; t < NTW; ++t) {
      int col = (ntb + t) * 16 + cb;
      float bv = bias[col];
#pragma unroll
      for (int r = 0; r < 4; ++r) {
        int gr = row0 + m0 + rg + r;
        Y[(size_t)gr * NOUT + col] = f2bf((acc[t][r] + bv) * inv[gr]);
      }
    }
  } else {
    // EPI_IN / EPI_LNRES: stage to cs, then row-wise epilogue, bf16 u32 stores
    __syncthreads();  // xs (union alias) may still be read by other waves
#pragma unroll
    for (int t = 0; t < NTW; ++t) {
      int col = (ntb + t) * 16 + cb;
      float bv = bias[col];
#pragma unroll
      for (int r = 0; r < 4; ++r) sh.cs[m0 + rg + r][col] = acc[t][r] + bv;
    }
    __syncthreads();
    u32* Y = (u32*)Yv;
    if constexpr (EPI == EPI_IN) {
      for (int rr = 0; rr < 8; ++rr) {
        int r = wid * 8 + rr;
        int gr = row0 + r;
        float2 t2 = *(const float2*)&sh.cs[r][lane * 2];
        Y[(size_t)gr * 64 + lane] = pack2(fmaxf(t2.x, 0.f), fmaxf(t2.y, 0.f));
      }
    } else {  // EPI_LNRES
      const u32* res = (const u32*)resv;
      float2 gg = *(const float2*)&g1[lane * 2];
      float2 bb = *(const float2*)&lb1[lane * 2];
      for (int rr = 0; rr < 8; ++rr) {
        int r = wid * 8 + rr;
        int gr = row0 + r;
        float2 t2 = *(const float2*)&sh.cs[r][lane * 2];
        u32 hv = res[(size_t)gr * 64 + lane];
        float tx = t2.x + bflo(hv), ty = t2.y + bfhi(hv);
        float mean = wred(tx + ty) * (1.f / 128.f);
        float dx = tx - mean, dy = ty - mean;
        float var = wred(dx * dx + dy * dy) * (1.f / 128.f);
        float rstd = rsqrtf(var + 1e-5f);
        float y0 = fmaxf(dx * rstd * gg.x + bb.x, 0.f);
        float y1 = fmaxf(dy * rstd * gg.y + bb.y, 0.f);
        Y[(size_t)gr * 64 + lane] = pack2(y0, y1);
      }
    }
  }
}

// ---------------------------------------------------------------------------
extern "C" void kernel_launch(void* const* d_in, const int* in_sizes, int n_in,
                              void* d_out, int out_size, void* d_ws, size_t ws_size,
                              hipStream_t stream) {
  (void)n_in; (void)out_size; (void)ws_size;
  const float* x      = (const float*)d_in[0];
  const int*   eidx   = (const int*)d_in[1];
  const float* degree = (const float*)d_in[2];
  const float* Win    = (const float*)d_in[3];
  const float* b_in   = (const float*)d_in[4];
  const float* W1     = (const float*)d_in[5];
  const float* b1     = (const float*)d_in[6];
  const float* W2     = (const float*)d_in[7];
  const float* b2     = (const float*)d_in[8];
  const float* ln_g   = (const float*)d_in[9];
  const float* ln_b   = (const float*)d_in[10];
  const float* out_g  = (const float*)d_in[11];
  const float* out_b  = (const float*)d_in[12];
  const float* Wout   = (const float*)d_in[13];
  const float* b_out  = (const float*)d_in[14];

  const int N = in_sizes[0] / 128;
  const int E = in_sizes[1] / 2;
  const int* esrc = eidx;
  const int* edst = eidx + E;

  char* p = (char*)d_ws;
  auto alloc = [&](size_t bytes) {
    char* q = p;
    p += (bytes + 255) & ~(size_t)255;
    return q;
  };
  float* inv    = (float*)alloc((size_t)N * 4);
  int*   offs   = (int*)alloc(((size_t)N + 1) * 4);
  int*   gcur   = (int*)alloc(256 * 4);
  int*   bsum   = (int*)alloc(1024 * 4);
  int*   col    = (int*)alloc((size_t)E * 4);
  uint2* pairs  = (uint2*)alloc((size_t)E * 8);
  u32*   h      = (u32*)alloc((size_t)N * 128 * 2);     // bf16 residual stream
  u32*   msc    = (u32*)alloc((size_t)N * 128 * 2);     // bf16
  u32*   agg    = (u32*)alloc((size_t)N * 128 * 2);     // bf16
  u16*   pWin   = (u16*)alloc(4 * 8 * 64 * 8 * 2);
  u16*   pWout  = (u16*)alloc(4 * 4 * 64 * 8 * 2);
  u16*   pW1    = (u16*)alloc(3 * 4 * 8 * 64 * 8 * 2);
  u16*   pW2    = (u16*)alloc(3 * 4 * 8 * 64 * 8 * 2);

  pack_w_k<<<8, 256, 0, stream>>>(Win, pWin, 128);
  for (int l = 0; l < 3; ++l) {
    pack_w_k<<<8, 256, 0, stream>>>(W1 + (size_t)l * 128 * 128, pW1 + (size_t)l * 16384, 128);
    pack_w_k<<<8, 256, 0, stream>>>(W2 + (size_t)l * 128 * 128, pW2 + (size_t)l * 16384, 128);
  }
  pack_w_k<<<4, 256, 0, stream>>>(Wout, pWout, 64);

  const int nb = (N + 255) / 256;
  const int NB = (N + 511) / 512;              // dst buckets of 512 nodes
  scan_block_k<<<nb, 256, 0, stream>>>(degree, offs, bsum, N);
  scan_bsum_k<<<1, 1024, 0, stream>>>(bsum, nb);
  scan_add_k<<<(N + 256) / 256, 256, 0, stream>>>(offs, bsum, gcur, inv, degree, N, E);
  scatter_k<<<(E + 8191) / 8192, 256, 0, stream>>>(esrc, edst, gcur, pairs, E);
  fill2_k<<<NB, 256, 0, stream>>>(pairs, offs, col, N);

  const int gemmGrid = (N + 31) / 32;
  const int rowGrid  = (N + 3) / 4;

  gemm_mfma<128, PREP_F32, EPI_IN><<<gemmGrid, 256, 0, stream>>>(
      x, pWin, b_in, h, nullptr, nullptr, nullptr, N);
  for (int l = 0; l < 3; ++l) {
    gemm_mfma<128, PREP_BF16, EPI_SCALE><<<gemmGrid, 256, 0, stream>>>(
        h, pW1 + (size_t)l * 16384, b1 + l * 128, msc, inv, nullptr, nullptr, N);
    spmm_k<<<rowGrid, 256, 0, stream>>>((const uint4*)msc, offs, col, inv, (uint4*)agg, N);
    gemm_mfma<128, PREP_BF16, EPI_LNRES><<<gemmGrid, 256, 0, stream>>>(
        agg, pW2 + (size_t)l * 16384, b2 + l * 128, h, h,
        ln_g + l * 128, ln_b + l * 128, N);
  }
  gemm_mfma<64, PREP_LN, EPI_NONE><<<gemmGrid, 256, 0, stream>>>(
      h, pWout, b_out, d_out, nullptr, out_g, out_b, N);
}